// Round 6
// baseline (669.184 us; speedup 1.0000x reference)
//
#include <hip/hip_runtime.h>

// Problem constants (fixed by setup_inputs)
#define T_TOK 8192
#define D_HID 1280
#define H_    16
#define HD_   80
#define C_    8
#define L_    1024
#define N3_   3840
#define QPAD  96     // Q/K head-dim padded to 96 (3 x K=32 MFMA steps)

typedef _Float16 f16;
typedef __attribute__((ext_vector_type(8))) _Float16 h8;   // MFMA A/B frag (4 VGPR)
typedef __attribute__((ext_vector_type(4))) float f32x4;   // MFMA C/D frag

// ---------------------------------------------------------------------------
// convert_x: fp32 -> fp16, same layout. 4 elems/thread.
// ---------------------------------------------------------------------------
__global__ __launch_bounds__(256) void convert_x(const float* __restrict__ x,
                                                 f16* __restrict__ y) {
  const int g = blockIdx.x * 256 + threadIdx.x;
  const float4 v = ((const float4*)x)[g];
  f16 o[4] = {(f16)v.x, (f16)v.y, (f16)v.z, (f16)v.w};
  ((uint2*)y)[g] = *(const uint2*)o;
}

// ---------------------------------------------------------------------------
// convert_w_t: W[K][N] fp32 -> Wt[N][K] fp16 (transposed for B^T GEMM).
// ---------------------------------------------------------------------------
__global__ __launch_bounds__(256) void convert_w_t(const float* __restrict__ W,
                                                   f16* __restrict__ Wt,
                                                   int K, int N) {
  __shared__ float tile[32][33];
  const int n0 = blockIdx.x * 32, k0 = blockIdx.y * 32;
  const int c = threadIdx.x & 31, r0 = threadIdx.x >> 5;
#pragma unroll
  for (int it = 0; it < 4; ++it) {
    const int r = r0 + it * 8;
    tile[r][c] = W[(size_t)(k0 + r) * N + n0 + c];
  }
  __syncthreads();
#pragma unroll
  for (int it = 0; it < 4; ++it) {
    const int r = r0 + it * 8;
    Wt[(size_t)(n0 + r) * K + k0 + c] = (f16)tile[c][r];
  }
}

// ---------------------------------------------------------------------------
// gemm_f16: C = A @ B^T + bias, fp16 in, fp32 MFMA accumulate.
// ZERO-LDS / ZERO-BARRIER: MFMA fragments are read directly from global
// (contiguous 16B per lane; A panel + W fit in L3, tiles hot in L1/L2).
// Register double-buffer: load frags for k+32 while MFMAs of k issue ->
// compiler emits interleaved buffer_load/MFMA with fine-grained vmcnt
// (the AITER pattern) and waves drift freely with no barrier drains.
// Block = 128x128 C-tile, 4 waves, each wave 64x64 (4x4 16x16 tiles).
// ---------------------------------------------------------------------------
__global__ __launch_bounds__(256) void gemm_f16(
    const f16* __restrict__ A, const f16* __restrict__ B,
    const float* __restrict__ bias,
    float* __restrict__ Cf, f16* __restrict__ Ch,
    int M, int N, int K) {
  const int tid = threadIdx.x;
  const int wave = tid >> 6, lane = tid & 63;
  const int quad = lane >> 4, ln = lane & 15;
  const int bm = blockIdx.y * 128, bn = blockIdx.x * 128;
  const int wm = (wave >> 1) * 64, wn = (wave & 1) * 64;

  // per-lane frag base pointers (k-chunk quad*8 folded in)
  const f16* Ap = A + (size_t)(bm + wm + ln) * K + quad * 8;
  const f16* Bp = B + (size_t)(bn + wn + ln) * K + quad * 8;
  const size_t r16 = (size_t)16 * K;   // 16-row stride

  f32x4 acc[4][4];
#pragma unroll
  for (int i = 0; i < 4; ++i)
#pragma unroll
    for (int j = 0; j < 4; ++j) acc[i][j] = (f32x4){0.f, 0.f, 0.f, 0.f};

  h8 af[4], bf[4];
#pragma unroll
  for (int i = 0; i < 4; ++i) af[i] = *(const h8*)(Ap + i * r16);
#pragma unroll
  for (int j = 0; j < 4; ++j) bf[j] = *(const h8*)(Bp + j * r16);

#pragma unroll 2
  for (int k0 = 32; k0 < K; k0 += 32) {
    h8 afn[4], bfn[4];
#pragma unroll
    for (int i = 0; i < 4; ++i) afn[i] = *(const h8*)(Ap + i * r16 + k0);
#pragma unroll
    for (int j = 0; j < 4; ++j) bfn[j] = *(const h8*)(Bp + j * r16 + k0);
#pragma unroll
    for (int i = 0; i < 4; ++i)
#pragma unroll
      for (int j = 0; j < 4; ++j)
        acc[i][j] = __builtin_amdgcn_mfma_f32_16x16x32_f16(af[i], bf[j], acc[i][j], 0, 0, 0);
#pragma unroll
    for (int i = 0; i < 4; ++i) af[i] = afn[i];
#pragma unroll
    for (int j = 0; j < 4; ++j) bf[j] = bfn[j];
  }
#pragma unroll
  for (int i = 0; i < 4; ++i)
#pragma unroll
    for (int j = 0; j < 4; ++j)
      acc[i][j] = __builtin_amdgcn_mfma_f32_16x16x32_f16(af[i], bf[j], acc[i][j], 0, 0, 0);

  float bv[4];
#pragma unroll
  for (int j = 0; j < 4; ++j) bv[j] = bias[bn + wn + j * 16 + ln];
#pragma unroll
  for (int i = 0; i < 4; ++i)
#pragma unroll
    for (int j = 0; j < 4; ++j)
#pragma unroll
      for (int r = 0; r < 4; ++r) {
        const int row = bm + wm + i * 16 + quad * 4 + r;   // C: row=quad*4+reg
        const int col = bn + wn + j * 16 + ln;             //    col=lane&15
        const float val = acc[i][j][r] + bv[j];
        if (Ch) Ch[(size_t)row * N + col] = (f16)val;
        else    Cf[(size_t)row * N + col] = val;
      }
}

// ---------------------------------------------------------------------------
// rope_convert: fp16 qkv -> RoPE'd Qb/Kb, head-major [h][t][96] ZERO-PADDED
// (cols 80..95). Softmax scale folded into Qb.
// ---------------------------------------------------------------------------
__global__ __launch_bounds__(256) void rope_convert(
    const f16* __restrict__ qkv, const float* __restrict__ cosb,
    const float* __restrict__ sinb, f16* __restrict__ Qb, f16* __restrict__ Kb) {
  const int t = blockIdx.x;
  const int tid = threadIdx.x;
  const size_t rowb = (size_t)t * N3_;
  const float scale = 0.11180339887498949f;
#pragma unroll
  for (int u = 0; u < 10; ++u) {
    const int e = tid + u * 256;              // 0..2559 (q then k)
    const int d = e % HD_;
    const bool lo = d < 40;
    const float v = (float)qkv[rowb + e];
    const float p = (float)qkv[rowb + (lo ? e + 40 : e - 40)];
    const float cs = cosb[(size_t)t * HD_ + d];
    const float sn = sinb[(size_t)t * HD_ + d];
    const float o = v * cs + (lo ? -p : p) * sn;
    const int h = (e % D_HID) / HD_;
    const size_t off = ((size_t)h * T_TOK + t) * QPAD + d;
    if (e < D_HID) Qb[off] = (f16)(o * scale);
    else           Kb[off] = (f16)o;
  }
  // zero pad columns 80..95 (ws is poisoned 0xAA)
  if (tid < 64) {
    const int qk = tid >> 5, h = (tid >> 1) & 15, half = tid & 1;
    f16* dst = (qk ? Kb : Qb) + ((size_t)h * T_TOK + t) * QPAD + 80 + half * 8;
    const int4 z = make_int4(0, 0, 0, 0);
    *(int4*)dst = z;
  }
}

// ---------------------------------------------------------------------------
// vt_convert: v (fp16, cols 2560..3839 of qkv) -> Vt[h][d][t] (transposed).
// ---------------------------------------------------------------------------
__global__ __launch_bounds__(256) void vt_convert(const f16* __restrict__ qkv,
                                                  f16* __restrict__ Vt) {
  __shared__ f16 tl[HD_][136];
  const int h = blockIdx.x & 15;
  const int t0 = (blockIdx.x >> 4) * 128;
  const int tid = threadIdx.x;
#pragma unroll
  for (int it = 0; it < 5; ++it) {
    const int e = tid + it * 256;
    const int t = e / 10, pc = e % 10;
    int4 v = *(const int4*)(qkv + (size_t)(t0 + t) * N3_ + 2 * D_HID + h * HD_ + pc * 8);
    f16 tmp[8];
    *(int4*)tmp = v;
#pragma unroll
    for (int u = 0; u < 8; ++u) tl[pc * 8 + u][t] = tmp[u];
  }
  __syncthreads();
#pragma unroll
  for (int it = 0; it < 5; ++it) {
    const int e = tid + it * 256;
    const int d = e >> 4, pt = e & 15;
    *(int4*)(Vt + ((size_t)h * HD_ + d) * T_TOK + t0 + pt * 8) = *(const int4*)&tl[d][pt * 8];
  }
}

// ---------------------------------------------------------------------------
// attn_flash: BARRIER-FREE flash attention (unchanged from R4/R5).
// ---------------------------------------------------------------------------
__global__ __launch_bounds__(256, 2) void attn_flash(
    const f16* __restrict__ Qb, const f16* __restrict__ Kb,
    const f16* __restrict__ Vt, f16* __restrict__ Oa) {
  __shared__ f16 Ps[4][64][72];              // per-wave P tile, stride 72
  const int tid = threadIdx.x;
  const int wave = tid >> 6, lane = tid & 63;
  const int quad = lane >> 4, ln = lane & 15;
  const int h = blockIdx.x & 15;
  const int qb = (blockIdx.x >> 4) & 3;
  const int c = blockIdx.x >> 6;
  const int t0 = c * L_ + qb * 256 + wave * 64;
  const size_t hb = (size_t)h * T_TOK;

  h8 aq[4][3];
#pragma unroll
  for (int i = 0; i < 4; ++i)
#pragma unroll
    for (int ks = 0; ks < 3; ++ks)
      aq[i][ks] = *(const h8*)(Qb + (hb + t0 + i * 16 + ln) * QPAD + ks * 32 + quad * 8);

  f32x4 o[4][5];
  float lsum[4][4];
#pragma unroll
  for (int i = 0; i < 4; ++i) {
#pragma unroll
    for (int jn = 0; jn < 5; ++jn) o[i][jn] = (f32x4){0.f, 0.f, 0.f, 0.f};
#pragma unroll
    for (int r = 0; r < 4; ++r) lsum[i][r] = 0.f;
  }

  for (int kb = 0; kb < 16; ++kb) {
    const int kt0 = c * L_ + kb * 64;
#pragma unroll
    for (int j = 0; j < 4; ++j) {
      h8 bk[3];
#pragma unroll
      for (int ks = 0; ks < 3; ++ks)
        bk[ks] = *(const h8*)(Kb + (hb + kt0 + j * 16 + ln) * QPAD + ks * 32 + quad * 8);
      f32x4 s[4];
#pragma unroll
      for (int i = 0; i < 4; ++i) s[i] = (f32x4){0.f, 0.f, 0.f, 0.f};
#pragma unroll
      for (int ks = 0; ks < 3; ++ks)
#pragma unroll
        for (int i = 0; i < 4; ++i)
          s[i] = __builtin_amdgcn_mfma_f32_16x16x32_f16(aq[i][ks], bk[ks], s[i], 0, 0, 0);
#pragma unroll
      for (int i = 0; i < 4; ++i)
#pragma unroll
        for (int r = 0; r < 4; ++r) {
          const float p = __expf(s[i][r]);
          lsum[i][r] += p;
          Ps[wave][i * 16 + quad * 4 + r][j * 16 + ln] = (f16)p;
        }
    }
#pragma unroll
    for (int ks = 0; ks < 2; ++ks) {
      h8 ap[4];
#pragma unroll
      for (int i = 0; i < 4; ++i)
        ap[i] = *(const h8*)&Ps[wave][i * 16 + ln][ks * 32 + quad * 8];
#pragma unroll
      for (int jn = 0; jn < 5; ++jn) {
        const h8 bv = *(const h8*)(Vt + ((size_t)h * HD_ + jn * 16 + ln) * T_TOK
                                   + kt0 + ks * 32 + quad * 8);
#pragma unroll
        for (int i = 0; i < 4; ++i)
          o[i][jn] = __builtin_amdgcn_mfma_f32_16x16x32_f16(ap[i], bv, o[i][jn], 0, 0, 0);
      }
    }
  }

#pragma unroll
  for (int i = 0; i < 4; ++i)
#pragma unroll
    for (int r = 0; r < 4; ++r) {
      float s = lsum[i][r];
#pragma unroll
      for (int off = 1; off < 16; off <<= 1) s += __shfl_xor(s, off);
      lsum[i][r] = 1.f / s;
    }

#pragma unroll
  for (int i = 0; i < 4; ++i)
#pragma unroll
    for (int r = 0; r < 4; ++r) {
      const int t = t0 + i * 16 + quad * 4 + r;
      const float inv = lsum[i][r];
#pragma unroll
      for (int jn = 0; jn < 5; ++jn)
        Oa[(size_t)t * D_HID + h * HD_ + jn * 16 + ln] = (f16)(o[i][jn][r] * inv);
    }
}

// ---------------------------------------------------------------------------
extern "C" void kernel_launch(void* const* d_in, const int* in_sizes, int n_in,
                              void* d_out, int out_size, void* d_ws, size_t ws_size,
                              hipStream_t stream) {
  (void)in_sizes; (void)n_in; (void)out_size; (void)ws_size;
  const float* x      = (const float*)d_in[0];
  const float* cosb   = (const float*)d_in[1];
  const float* sinb   = (const float*)d_in[2];
  const float* w_qkv  = (const float*)d_in[3];
  const float* b_qkv  = (const float*)d_in[4];
  const float* w_proj = (const float*)d_in[5];
  const float* b_proj = (const float*)d_in[6];
  float* out = (float*)d_out;

  // workspace map (bytes):
  //  [0)           qkv f16    62,914,560  } aliased by attn O (21 MB) post-vt
  //  [62914560)    Qb [16][8192][96]  25,165,824
  //  [88080384)    Kb [16][8192][96]  25,165,824
  //  [113246208)   Vt [16][80][8192]  20,971,520
  //  [134217728)   Wqkv_t              9,830,400
  //  [144048128)   Wproj_t             3,276,800   -> end 147,324,928
  char* ws = (char*)d_ws;
  f16* qkv_h  = (f16*)(ws);
  f16* attn_h = (f16*)(ws);                          // alias (post-attention)
  f16* x_h    = (f16*)(ws + 62914560);               // temp in Qb slot
  f16* Qb     = (f16*)(ws + 62914560);               // alias (post-GEMM1)
  f16* Kb     = (f16*)(ws + 88080384);
  f16* Vt     = (f16*)(ws + 113246208);
  f16* wq_t   = (f16*)(ws + 134217728);
  f16* wp_t   = (f16*)(ws + 144048128);

  // 1) fp16 conversions (X, W^T)
  convert_x<<<(T_TOK * D_HID / 4) / 256, 256, 0, stream>>>(x, x_h);
  convert_w_t<<<dim3(N3_ / 32, D_HID / 32), 256, 0, stream>>>(w_qkv, wq_t, D_HID, N3_);
  convert_w_t<<<dim3(D_HID / 32, D_HID / 32), 256, 0, stream>>>(w_proj, wp_t, D_HID, D_HID);
  // 2) qkv = x @ w_qkv + b_qkv  (fp16 out)
  gemm_f16<<<dim3(N3_ / 128, T_TOK / 128), 256, 0, stream>>>(
      x_h, wq_t, b_qkv, nullptr, qkv_h, T_TOK, N3_, D_HID);
  // 3) RoPE + head-major padded fp16 Q/K (scale folded into Q)
  rope_convert<<<T_TOK, 256, 0, stream>>>(qkv_h, cosb, sinb, Qb, Kb);
  // 4) V transpose to [h][d][t]
  vt_convert<<<H_ * (T_TOK / 128), 256, 0, stream>>>(qkv_h, Vt);
  // 5) barrier-free flash attention -> attn fp16 [t][1280]
  attn_flash<<<C_ * 4 * H_, 256, 0, stream>>>(Qb, Kb, Vt, attn_h);
  // 6) out = attn @ w_proj + b_proj  (fp32 out)
  gemm_f16<<<dim3(D_HID / 128, T_TOK / 128), 256, 0, stream>>>(
      attn_h, wp_t, b_proj, out, nullptr, T_TOK, D_HID, D_HID);
}

// Round 7
// 401.006 us; speedup vs baseline: 1.6688x; 1.6688x over previous
//
#include <hip/hip_runtime.h>

// Problem constants (fixed by setup_inputs)
#define T_TOK 8192
#define D_HID 1280
#define H_    16
#define HD_   80
#define C_    8
#define L_    1024
#define N3_   3840
#define QPAD  96     // Q/K head-dim padded to 96 (3 x K=32 MFMA steps)

typedef _Float16 f16;
typedef __attribute__((ext_vector_type(8))) _Float16 h8;   // MFMA A/B frag (4 VGPR)
typedef __attribute__((ext_vector_type(4))) float f32x4;   // MFMA C/D frag

// ---------------------------------------------------------------------------
// convert_x: fp32 -> fp16, same layout. 4 elems/thread.
// ---------------------------------------------------------------------------
__global__ __launch_bounds__(256) void convert_x(const float* __restrict__ x,
                                                 f16* __restrict__ y) {
  const int g = blockIdx.x * 256 + threadIdx.x;
  const float4 v = ((const float4*)x)[g];
  f16 o[4] = {(f16)v.x, (f16)v.y, (f16)v.z, (f16)v.w};
  ((uint2*)y)[g] = *(const uint2*)o;
}

// ---------------------------------------------------------------------------
// convert_w_t: W[K][N] fp32 -> Wt[N][K] fp16 (transposed for B^T GEMM).
// ---------------------------------------------------------------------------
__global__ __launch_bounds__(256) void convert_w_t(const float* __restrict__ W,
                                                   f16* __restrict__ Wt,
                                                   int K, int N) {
  __shared__ float tile[32][33];
  const int n0 = blockIdx.x * 32, k0 = blockIdx.y * 32;
  const int c = threadIdx.x & 31, r0 = threadIdx.x >> 5;
#pragma unroll
  for (int it = 0; it < 4; ++it) {
    const int r = r0 + it * 8;
    tile[r][c] = W[(size_t)(k0 + r) * N + n0 + c];
  }
  __syncthreads();
#pragma unroll
  for (int it = 0; it < 4; ++it) {
    const int r = r0 + it * 8;
    Wt[(size_t)(n0 + r) * K + k0 + c] = (f16)tile[c][r];
  }
}

// ---------------------------------------------------------------------------
// gemm_f16: C = A @ B^T + bias, fp16 in, fp32 MFMA accumulate.
// Block tile 128x256, BK=64. 4 waves; each wave owns a 64x128 C-tile
// (4x8 16x16 tiles, 128 acc VGPRs): LDS bytes/FLOP is 0.75x the 64x64
// config (R5 was LDS-read-BW-bound: 16 KB ds_read per 262 KFLOP per wave;
// now 24 KB per 524 KFLOP). Staging via global_load_lds w16 with the R5
// XOR swizzle (measured 0 bank conflicts).
// ---------------------------------------------------------------------------
__device__ __forceinline__ void stage_rows(const f16* __restrict__ gbase, int K,
                                           f16* sdst, int nchunks, int tid) {
  // nchunks = rows*8, each 16B; 256 threads
  for (int s0 = 0; s0 < nchunks; s0 += 256) {
    const int s = s0 + tid;
    const int row = s >> 3;
    const int part = (s & 7) ^ (row & 7);           // XOR swizzle
    const f16* gp = gbase + (size_t)row * K + part * 8;
    __builtin_amdgcn_global_load_lds(
        (const __attribute__((address_space(1))) void*)gp,
        (__attribute__((address_space(3))) void*)(sdst + s * 8),
        16, 0, 0);
  }
}

__device__ __forceinline__ h8 fragld64(const f16* s, int row, int c) {
  const int slot = c ^ (row & 7);                   // c = ks*4 + quad
  return *(const h8*)&s[row * 64 + slot * 8];
}

__global__ __launch_bounds__(256, 2) void gemm_f16(
    const f16* __restrict__ A, const f16* __restrict__ B,
    const float* __restrict__ bias,
    float* __restrict__ Cf, f16* __restrict__ Ch,
    int M, int N, int K) {
  __shared__ f16 sA[128 * 64], sB[256 * 64];
  const int tid = threadIdx.x;
  const int wave = tid >> 6, lane = tid & 63;
  const int quad = lane >> 4, ln = lane & 15;
  const int bm = blockIdx.y * 128, bn = blockIdx.x * 256;
  const int wm = (wave >> 1) * 64, wn = (wave & 1) * 128;

  f32x4 acc[4][8];
#pragma unroll
  for (int i = 0; i < 4; ++i)
#pragma unroll
    for (int j = 0; j < 8; ++j) acc[i][j] = (f32x4){0.f, 0.f, 0.f, 0.f};

  for (int k0 = 0; k0 < K; k0 += 64) {
    __syncthreads();
    stage_rows(A + (size_t)bm * K + k0, K, sA, 128 * 8, tid);
    stage_rows(B + (size_t)bn * K + k0, K, sB, 256 * 8, tid);
    __syncthreads();

#pragma unroll
    for (int ks = 0; ks < 2; ++ks) {
      h8 af[4], bf[8];
#pragma unroll
      for (int i = 0; i < 4; ++i) af[i] = fragld64(sA, wm + i * 16 + ln, ks * 4 + quad);
#pragma unroll
      for (int j = 0; j < 8; ++j) bf[j] = fragld64(sB, wn + j * 16 + ln, ks * 4 + quad);
#pragma unroll
      for (int i = 0; i < 4; ++i)
#pragma unroll
        for (int j = 0; j < 8; ++j)
          acc[i][j] = __builtin_amdgcn_mfma_f32_16x16x32_f16(af[i], bf[j], acc[i][j], 0, 0, 0);
    }
  }

  float bv[8];
#pragma unroll
  for (int j = 0; j < 8; ++j) bv[j] = bias[bn + wn + j * 16 + ln];
#pragma unroll
  for (int i = 0; i < 4; ++i)
#pragma unroll
    for (int j = 0; j < 8; ++j)
#pragma unroll
      for (int r = 0; r < 4; ++r) {
        const int row = bm + wm + i * 16 + quad * 4 + r;   // C: row=quad*4+reg
        const int col = bn + wn + j * 16 + ln;             //    col=lane&15
        const float val = acc[i][j][r] + bv[j];
        if (Ch) Ch[(size_t)row * N + col] = (f16)val;
        else    Cf[(size_t)row * N + col] = val;
      }
}

// ---------------------------------------------------------------------------
// rope_convert: fp16 qkv -> RoPE'd Qb/Kb, head-major [h][t][96] ZERO-PADDED
// (cols 80..95). Softmax scale folded into Qb.
// ---------------------------------------------------------------------------
__global__ __launch_bounds__(256) void rope_convert(
    const f16* __restrict__ qkv, const float* __restrict__ cosb,
    const float* __restrict__ sinb, f16* __restrict__ Qb, f16* __restrict__ Kb) {
  const int t = blockIdx.x;
  const int tid = threadIdx.x;
  const size_t rowb = (size_t)t * N3_;
  const float scale = 0.11180339887498949f;
#pragma unroll
  for (int u = 0; u < 10; ++u) {
    const int e = tid + u * 256;              // 0..2559 (q then k)
    const int d = e % HD_;
    const bool lo = d < 40;
    const float v = (float)qkv[rowb + e];
    const float p = (float)qkv[rowb + (lo ? e + 40 : e - 40)];
    const float cs = cosb[(size_t)t * HD_ + d];
    const float sn = sinb[(size_t)t * HD_ + d];
    const float o = v * cs + (lo ? -p : p) * sn;
    const int h = (e % D_HID) / HD_;
    const size_t off = ((size_t)h * T_TOK + t) * QPAD + d;
    if (e < D_HID) Qb[off] = (f16)(o * scale);
    else           Kb[off] = (f16)o;
  }
  // zero pad columns 80..95 (ws is poisoned 0xAA)
  if (tid < 64) {
    const int qk = tid >> 5, h = (tid >> 1) & 15, half = tid & 1;
    f16* dst = (qk ? Kb : Qb) + ((size_t)h * T_TOK + t) * QPAD + 80 + half * 8;
    const int4 z = make_int4(0, 0, 0, 0);
    *(int4*)dst = z;
  }
}

// ---------------------------------------------------------------------------
// vt_convert: v (fp16, cols 2560..3839 of qkv) -> Vt[h][d][t] (transposed).
// ---------------------------------------------------------------------------
__global__ __launch_bounds__(256) void vt_convert(const f16* __restrict__ qkv,
                                                  f16* __restrict__ Vt) {
  __shared__ f16 tl[HD_][136];
  const int h = blockIdx.x & 15;
  const int t0 = (blockIdx.x >> 4) * 128;
  const int tid = threadIdx.x;
#pragma unroll
  for (int it = 0; it < 5; ++it) {
    const int e = tid + it * 256;
    const int t = e / 10, pc = e % 10;
    int4 v = *(const int4*)(qkv + (size_t)(t0 + t) * N3_ + 2 * D_HID + h * HD_ + pc * 8);
    f16 tmp[8];
    *(int4*)tmp = v;
#pragma unroll
    for (int u = 0; u < 8; ++u) tl[pc * 8 + u][t] = tmp[u];
  }
  __syncthreads();
#pragma unroll
  for (int it = 0; it < 5; ++it) {
    const int e = tid + it * 256;
    const int d = e >> 4, pt = e & 15;
    *(int4*)(Vt + ((size_t)h * HD_ + d) * T_TOK + t0 + pt * 8) = *(const int4*)&tl[d][pt * 8];
  }
}

// ---------------------------------------------------------------------------
// attn_flash: BARRIER-FREE flash attention (unchanged from R4/R5).
// ---------------------------------------------------------------------------
__global__ __launch_bounds__(256, 2) void attn_flash(
    const f16* __restrict__ Qb, const f16* __restrict__ Kb,
    const f16* __restrict__ Vt, f16* __restrict__ Oa) {
  __shared__ f16 Ps[4][64][72];              // per-wave P tile, stride 72
  const int tid = threadIdx.x;
  const int wave = tid >> 6, lane = tid & 63;
  const int quad = lane >> 4, ln = lane & 15;
  const int h = blockIdx.x & 15;
  const int qb = (blockIdx.x >> 4) & 3;
  const int c = blockIdx.x >> 6;
  const int t0 = c * L_ + qb * 256 + wave * 64;
  const size_t hb = (size_t)h * T_TOK;

  h8 aq[4][3];
#pragma unroll
  for (int i = 0; i < 4; ++i)
#pragma unroll
    for (int ks = 0; ks < 3; ++ks)
      aq[i][ks] = *(const h8*)(Qb + (hb + t0 + i * 16 + ln) * QPAD + ks * 32 + quad * 8);

  f32x4 o[4][5];
  float lsum[4][4];
#pragma unroll
  for (int i = 0; i < 4; ++i) {
#pragma unroll
    for (int jn = 0; jn < 5; ++jn) o[i][jn] = (f32x4){0.f, 0.f, 0.f, 0.f};
#pragma unroll
    for (int r = 0; r < 4; ++r) lsum[i][r] = 0.f;
  }

  for (int kb = 0; kb < 16; ++kb) {
    const int kt0 = c * L_ + kb * 64;
#pragma unroll
    for (int j = 0; j < 4; ++j) {
      h8 bk[3];
#pragma unroll
      for (int ks = 0; ks < 3; ++ks)
        bk[ks] = *(const h8*)(Kb + (hb + kt0 + j * 16 + ln) * QPAD + ks * 32 + quad * 8);
      f32x4 s[4];
#pragma unroll
      for (int i = 0; i < 4; ++i) s[i] = (f32x4){0.f, 0.f, 0.f, 0.f};
#pragma unroll
      for (int ks = 0; ks < 3; ++ks)
#pragma unroll
        for (int i = 0; i < 4; ++i)
          s[i] = __builtin_amdgcn_mfma_f32_16x16x32_f16(aq[i][ks], bk[ks], s[i], 0, 0, 0);
#pragma unroll
      for (int i = 0; i < 4; ++i)
#pragma unroll
        for (int r = 0; r < 4; ++r) {
          const float p = __expf(s[i][r]);
          lsum[i][r] += p;
          Ps[wave][i * 16 + quad * 4 + r][j * 16 + ln] = (f16)p;
        }
    }
#pragma unroll
    for (int ks = 0; ks < 2; ++ks) {
      h8 ap[4];
#pragma unroll
      for (int i = 0; i < 4; ++i)
        ap[i] = *(const h8*)&Ps[wave][i * 16 + ln][ks * 32 + quad * 8];
#pragma unroll
      for (int jn = 0; jn < 5; ++jn) {
        const h8 bv = *(const h8*)(Vt + ((size_t)h * HD_ + jn * 16 + ln) * T_TOK
                                   + kt0 + ks * 32 + quad * 8);
#pragma unroll
        for (int i = 0; i < 4; ++i)
          o[i][jn] = __builtin_amdgcn_mfma_f32_16x16x32_f16(ap[i], bv, o[i][jn], 0, 0, 0);
      }
    }
  }

#pragma unroll
  for (int i = 0; i < 4; ++i)
#pragma unroll
    for (int r = 0; r < 4; ++r) {
      float s = lsum[i][r];
#pragma unroll
      for (int off = 1; off < 16; off <<= 1) s += __shfl_xor(s, off);
      lsum[i][r] = 1.f / s;
    }

#pragma unroll
  for (int i = 0; i < 4; ++i)
#pragma unroll
    for (int r = 0; r < 4; ++r) {
      const int t = t0 + i * 16 + quad * 4 + r;
      const float inv = lsum[i][r];
#pragma unroll
      for (int jn = 0; jn < 5; ++jn)
        Oa[(size_t)t * D_HID + h * HD_ + jn * 16 + ln] = (f16)(o[i][jn][r] * inv);
    }
}

// ---------------------------------------------------------------------------
extern "C" void kernel_launch(void* const* d_in, const int* in_sizes, int n_in,
                              void* d_out, int out_size, void* d_ws, size_t ws_size,
                              hipStream_t stream) {
  (void)in_sizes; (void)n_in; (void)out_size; (void)ws_size;
  const float* x      = (const float*)d_in[0];
  const float* cosb   = (const float*)d_in[1];
  const float* sinb   = (const float*)d_in[2];
  const float* w_qkv  = (const float*)d_in[3];
  const float* b_qkv  = (const float*)d_in[4];
  const float* w_proj = (const float*)d_in[5];
  const float* b_proj = (const float*)d_in[6];
  float* out = (float*)d_out;

  // workspace map (bytes):
  //  [0)           qkv f16    62,914,560  } aliased by attn O (21 MB) post-vt
  //  [62914560)    Qb [16][8192][96]  25,165,824
  //  [88080384)    Kb [16][8192][96]  25,165,824
  //  [113246208)   Vt [16][80][8192]  20,971,520
  //  [134217728)   Wqkv_t              9,830,400
  //  [144048128)   Wproj_t             3,276,800   -> end 147,324,928
  char* ws = (char*)d_ws;
  f16* qkv_h  = (f16*)(ws);
  f16* attn_h = (f16*)(ws);                          // alias (post-attention)
  f16* x_h    = (f16*)(ws + 62914560);               // temp in Qb slot
  f16* Qb     = (f16*)(ws + 62914560);               // alias (post-GEMM1)
  f16* Kb     = (f16*)(ws + 88080384);
  f16* Vt     = (f16*)(ws + 113246208);
  f16* wq_t   = (f16*)(ws + 134217728);
  f16* wp_t   = (f16*)(ws + 144048128);

  // 1) fp16 conversions (X, W^T)
  convert_x<<<(T_TOK * D_HID / 4) / 256, 256, 0, stream>>>(x, x_h);
  convert_w_t<<<dim3(N3_ / 32, D_HID / 32), 256, 0, stream>>>(w_qkv, wq_t, D_HID, N3_);
  convert_w_t<<<dim3(D_HID / 32, D_HID / 32), 256, 0, stream>>>(w_proj, wp_t, D_HID, D_HID);
  // 2) qkv = x @ w_qkv + b_qkv  (fp16 out)
  gemm_f16<<<dim3(N3_ / 256, T_TOK / 128), 256, 0, stream>>>(
      x_h, wq_t, b_qkv, nullptr, qkv_h, T_TOK, N3_, D_HID);
  // 3) RoPE + head-major padded fp16 Q/K (scale folded into Q)
  rope_convert<<<T_TOK, 256, 0, stream>>>(qkv_h, cosb, sinb, Qb, Kb);
  // 4) V transpose to [h][d][t]
  vt_convert<<<H_ * (T_TOK / 128), 256, 0, stream>>>(qkv_h, Vt);
  // 5) barrier-free flash attention -> attn fp16 [t][1280]
  attn_flash<<<C_ * 4 * H_, 256, 0, stream>>>(Qb, Kb, Vt, attn_h);
  // 6) out = attn @ w_proj + b_proj  (fp32 out)
  gemm_f16<<<dim3(D_HID / 256, T_TOK / 128), 256, 0, stream>>>(
      attn_h, wp_t, b_proj, out, nullptr, T_TOK, D_HID, D_HID);
}